// Round 7
// baseline (670.962 us; speedup 1.0000x reference)
//
#include <hip/hip_runtime.h>
#include <math.h>

// ============================================================================
// ViT block, fp32 in / fp32 out, bf16 internal, fp32 accum.
// B=16, N=1024, D=768, H=12, Hd=64, FF=3072, M=16384.
// r6 -> r7: GEMM K-loop software-pipelined with double-buffered
// global_load_lds staging (1 barrier/iter; DMA latency hidden behind the
// previous tile's MFMA+LDS work). Epilogues/attention unchanged from r6.
// ============================================================================

typedef unsigned short u16;
typedef __attribute__((ext_vector_type(8))) short bf16x8;
typedef __attribute__((ext_vector_type(4))) float f32x4;

#define MFMA_BF16(a, b, c) __builtin_amdgcn_mfma_f32_16x16x32_bf16((a), (b), (c), 0, 0, 0)

__device__ __forceinline__ float bf2f(u16 v) {
    return __uint_as_float(((unsigned)v) << 16);
}
__device__ __forceinline__ u16 f2bf(float f) {  // RNE
    unsigned u = __float_as_uint(f);
    u += 0x7fffu + ((u >> 16) & 1u);
    return (u16)(u >> 16);
}

typedef __attribute__((address_space(1))) const void gvoid;
typedef __attribute__((address_space(3))) void lvoid;
__device__ __forceinline__ void gll16(const void* g, void* l) {
    // async global->LDS DMA, 16 B/lane; LDS dest = wave-uniform base + lane*16
    __builtin_amdgcn_global_load_lds((gvoid*)g, (lvoid*)l, 16, 0, 0);
}

// ---------------------------------------------------------------------------
// fp32 -> bf16 cast (weights pre-cast, once per launch)
// ---------------------------------------------------------------------------
__global__ __launch_bounds__(256) void cast32(const float* __restrict__ src,
                                              u16* __restrict__ dst, int n8) {
    const int i = blockIdx.x * 256 + threadIdx.x;
    if (i >= n8) return;
    const float4 a = ((const float4*)src)[2 * i];
    const float4 b = ((const float4*)src)[2 * i + 1];
    bf16x8 r;
    r[0] = (short)f2bf(a.x); r[1] = (short)f2bf(a.y);
    r[2] = (short)f2bf(a.z); r[3] = (short)f2bf(a.w);
    r[4] = (short)f2bf(b.x); r[5] = (short)f2bf(b.y);
    r[6] = (short)f2bf(b.z); r[7] = (short)f2bf(b.w);
    ((bf16x8*)dst)[i] = r;
}

// ---------------------------------------------------------------------------
// LayerNorm (row of 768, 256 threads). fp32 in, bf16 out.
// ---------------------------------------------------------------------------
__global__ __launch_bounds__(256) void ln_kernel(const float* __restrict__ x,
                                                 const float* __restrict__ g,
                                                 const float* __restrict__ b,
                                                 u16* __restrict__ out) {
    const int row = blockIdx.x;
    const int t = threadIdx.x;
    const float* xr = x + (size_t)row * 768;
    float v0 = xr[t], v1 = xr[t + 256], v2 = xr[t + 512];
    float s = v0 + v1 + v2;
    float sq = v0 * v0 + v1 * v1 + v2 * v2;
#pragma unroll
    for (int off = 32; off > 0; off >>= 1) {
        s += __shfl_down(s, off);
        sq += __shfl_down(sq, off);
    }
    __shared__ float red_s[4], red_sq[4], sh_mu, sh_rs;
    const int wave = t >> 6, lane = t & 63;
    if (lane == 0) { red_s[wave] = s; red_sq[wave] = sq; }
    __syncthreads();
    if (t == 0) {
        float S = red_s[0] + red_s[1] + red_s[2] + red_s[3];
        float SQ = red_sq[0] + red_sq[1] + red_sq[2] + red_sq[3];
        float mu = S * (1.0f / 768.0f);
        float var = SQ * (1.0f / 768.0f) - mu * mu;
        sh_mu = mu;
        sh_rs = 1.0f / sqrtf(fmaxf(var, 0.0f) + 1e-6f);
    }
    __syncthreads();
    const float mu = sh_mu, rs = sh_rs;
    u16* orow = out + (size_t)row * 768;
    orow[t]       = f2bf((v0 - mu) * rs * g[t]       + b[t]);
    orow[t + 256] = f2bf((v1 - mu) * rs * g[t + 256] + b[t + 256]);
    orow[t + 512] = f2bf((v2 - mu) * rs * g[t + 512] + b[t + 512]);
}

// ---------------------------------------------------------------------------
// NT GEMM, 128x128 tile, BK=32, 4 waves, DOUBLE-BUFFERED DMA staging:
//   loop: __syncthreads(); issue DMA(kt+1 -> buf^1); compute(buf).
// The barrier's vmcnt(0) drain for tile kt lands one full compute phase after
// issue -> latency hidden; one barrier per iteration.
// BF16B=1: B bf16 via global_load_lds; BF16B=0: B fp32, VGPR cast staging.
// EPI: 1 = bias+GELU -> bf16; 2 = bias+residual(fp32) -> fp32;
//      3 = qkv split: q(*0.125),k -> qkkb[M][1536]; v -> vtb[b,h][hd][1024].
// ---------------------------------------------------------------------------
template <int EPI, int BF16B>
__global__ __launch_bounds__(256, 2) void gemm3(
        const u16* __restrict__ A, const void* __restrict__ Bv,
        const float* __restrict__ bias, const float* __restrict__ res,
        void* __restrict__ Cv, u16* __restrict__ vtb, int N, int K) {
    __shared__ __align__(16) u16 As[2][4096];
    __shared__ __align__(16) u16 Bs[2][4096];
    const int t = threadIdx.x;
    const int wave = t >> 6, lane = t & 63;
    const int quad = lane >> 4, mr = lane & 15;
    const int wm = wave >> 1, wn = wave & 1;
    const int m0 = blockIdx.y * 128;
    const int n0 = blockIdx.x * 128;

    f32x4 acc[4][4];
#pragma unroll
    for (int i = 0; i < 4; i++)
#pragma unroll
        for (int j = 0; j < 4; j++) acc[i][j] = (f32x4){0.f, 0.f, 0.f, 0.f};

    const int seg = wave * 2;          // DMA segment base (2 per wave)
    const int drow = lane >> 2;        // 0..15 within segment
    const int dcol = (lane & 3) * 8;   // u16 col
    const int sr = t >> 2, skv = t & 3;  // fallback-B staging

    const int nk = K >> 5;

    // ---- stage tile kt into buffer buf ----
    auto stage = [&](int kt, int buf) {
        const int k0 = kt * 32;
#pragma unroll
        for (int c = 0; c < 2; c++) {
            const int rowA = (seg + c) * 16 + drow;
            gll16(A + (size_t)(m0 + rowA) * K + k0 + dcol, &As[buf][(seg + c) * 512]);
        }
        if (BF16B) {
            const u16* Bh = (const u16*)Bv;
#pragma unroll
            for (int c = 0; c < 2; c++) {
                const int rowB = (seg + c) * 16 + drow;
                gll16(Bh + (size_t)(n0 + rowB) * K + k0 + dcol, &Bs[buf][(seg + c) * 512]);
            }
        } else {
            const float* Bf = (const float*)Bv;
#pragma unroll
            for (int half = 0; half < 2; half++) {
                const float* src = Bf + (size_t)(n0 + sr + half * 64) * K + k0 + skv * 8;
                const float4 a = *(const float4*)src;
                const float4 b2 = *(const float4*)(src + 4);
                bf16x8 r;
                r[0] = (short)f2bf(a.x);  r[1] = (short)f2bf(a.y);
                r[2] = (short)f2bf(a.z);  r[3] = (short)f2bf(a.w);
                r[4] = (short)f2bf(b2.x); r[5] = (short)f2bf(b2.y);
                r[6] = (short)f2bf(b2.z); r[7] = (short)f2bf(b2.w);
                *(bf16x8*)&Bs[buf][(sr + half * 64) * 32 + skv * 8] = r;
            }
        }
    };

    stage(0, 0);
    for (int kt = 0; kt < nk; ++kt) {
        const int cur = kt & 1;
        __syncthreads();                    // drains DMA(kt); orders buf reuse
        if (kt + 1 < nk) stage(kt + 1, cur ^ 1);
        bf16x8 af[4], bfr[4];
#pragma unroll
        for (int i = 0; i < 4; i++)
            af[i] = *(const bf16x8*)&As[cur][(wm * 64 + i * 16 + mr) * 32 + quad * 8];
#pragma unroll
        for (int j = 0; j < 4; j++)
            bfr[j] = *(const bf16x8*)&Bs[cur][(wn * 64 + j * 16 + mr) * 32 + quad * 8];
#pragma unroll
        for (int i = 0; i < 4; i++)
#pragma unroll
            for (int j = 0; j < 4; j++)
                acc[i][j] = MFMA_BF16(af[i], bfr[j], acc[i][j]);
    }

#pragma unroll
    for (int i = 0; i < 4; i++) {
#pragma unroll
        for (int r = 0; r < 4; r++) {
            const int m = m0 + wm * 64 + i * 16 + quad * 4 + r;
#pragma unroll
            for (int j = 0; j < 4; j++) {
                const int n = n0 + wn * 64 + j * 16 + mr;
                float v = acc[i][j][r] + bias[n];
                if (EPI == 1) {
                    v = 0.5f * v * (1.0f + erff(v * 0.70710678118f));
                    ((u16*)Cv)[(size_t)m * N + n] = f2bf(v);
                } else if (EPI == 2) {
                    v += res[(size_t)m * N + n];
                    ((float*)Cv)[(size_t)m * N + n] = v;
                } else {  // EPI == 3: qkv split
                    if (n < 1536) {
                        const float vq = (n < 768) ? v * 0.125f : v;
                        ((u16*)Cv)[(size_t)m * 1536 + n] = f2bf(vq);
                    } else {
                        const int h = (n - 1536) >> 6, hd = (n - 1536) & 63;
                        const int bb = m >> 10, pos = m & 1023;
                        vtb[((size_t)(bb * 12 + h) * 64 + hd) * 1024 + pos] = f2bf(v);
                    }
                }
            }
        }
    }
}

// ---------------------------------------------------------------------------
// Flash attention v2 (as r6). Block = (b,h) x 64 q-rows, 4 waves x 16 rows.
// qkkb [M][1536]: q(pre-scaled 0.125) @0, k @768. vtb [b*12+h][64 hd][1024].
// Fixed-max softmax p=exp(s-8); VGPR-prefetch double buffering.
// ---------------------------------------------------------------------------
__global__ __launch_bounds__(256) void attn2(const u16* __restrict__ qkkb,
                                             const u16* __restrict__ vtb,
                                             u16* __restrict__ ctx) {
    __shared__ __align__(16) u16 Ks[2][64][72];
    __shared__ __align__(16) u16 Vt[2][64][72];
    __shared__ __align__(16) u16 Ps[64][72];
    const int bh = blockIdx.y;
    const int b = bh / 12, h = bh % 12;
    const int q0 = blockIdx.x * 64;
    const int t = threadIdx.x;
    const int wave = t >> 6, lane = t & 63, quad = lane >> 4, mr = lane & 15;

    const u16* qrow = qkkb + (size_t)(b * 1024 + q0 + wave * 16 + mr) * 1536 + h * 64;
    const bf16x8 qf0 = *(const bf16x8*)(qrow + quad * 8);
    const bf16x8 qf1 = *(const bf16x8*)(qrow + 32 + quad * 8);

    const u16* kbase = qkkb + (size_t)b * 1024 * 1536 + 768 + h * 64;
    const u16* vbase = vtb + (size_t)bh * 64 * 1024;

    const int srow = t >> 3;  // 0..31 (two halves: +0, +32)
    const int sv = t & 7;     // 16B chunk

    f32x4 oacc[4];
#pragma unroll
    for (int j = 0; j < 4; j++) oacc[j] = (f32x4){0.f, 0.f, 0.f, 0.f};
    float lsum[4] = {0.f, 0.f, 0.f, 0.f};

    bf16x8 pk0, pk1, pv0, pv1;
    pk0 = *(const bf16x8*)(kbase + (size_t)(srow)      * 1536 + sv * 8);
    pk1 = *(const bf16x8*)(kbase + (size_t)(srow + 32) * 1536 + sv * 8);
    pv0 = *(const bf16x8*)(vbase + (size_t)(srow)      * 1024 + sv * 8);
    pv1 = *(const bf16x8*)(vbase + (size_t)(srow + 32) * 1024 + sv * 8);
    *(bf16x8*)&Ks[0][srow][sv * 8] = pk0;
    *(bf16x8*)&Ks[0][srow + 32][sv * 8] = pk1;
    *(bf16x8*)&Vt[0][srow][sv * 8] = pv0;
    *(bf16x8*)&Vt[0][srow + 32][sv * 8] = pv1;

    for (int kt = 0; kt < 16; ++kt) {
        __syncthreads();
        const int cur = kt & 1;
        if (kt < 15) {
            const size_t ko = (size_t)(kt + 1) * 64;
            pk0 = *(const bf16x8*)(kbase + (ko + srow)      * 1536 + sv * 8);
            pk1 = *(const bf16x8*)(kbase + (ko + srow + 32) * 1536 + sv * 8);
            pv0 = *(const bf16x8*)(vbase + (size_t)(srow)      * 1024 + ko + sv * 8);
            pv1 = *(const bf16x8*)(vbase + (size_t)(srow + 32) * 1024 + ko + sv * 8);
        }
        f32x4 sf[4];
#pragma unroll
        for (int j = 0; j < 4; j++) {
            const bf16x8 kf0 = *(const bf16x8*)&Ks[cur][j * 16 + mr][quad * 8];
            const bf16x8 kf1 = *(const bf16x8*)&Ks[cur][j * 16 + mr][32 + quad * 8];
            f32x4 s = (f32x4){0.f, 0.f, 0.f, 0.f};
            s = MFMA_BF16(qf0, kf0, s);
            s = MFMA_BF16(qf1, kf1, s);
            sf[j] = s;
        }
#pragma unroll
        for (int r = 0; r < 4; r++) {
            const float p0 = __expf(sf[0][r] - 8.0f);
            const float p1 = __expf(sf[1][r] - 8.0f);
            const float p2 = __expf(sf[2][r] - 8.0f);
            const float p3 = __expf(sf[3][r] - 8.0f);
            lsum[r] += (p0 + p1) + (p2 + p3);
            const int prow = wave * 16 + quad * 4 + r;
            Ps[prow][0 * 16 + mr] = f2bf(p0);
            Ps[prow][1 * 16 + mr] = f2bf(p1);
            Ps[prow][2 * 16 + mr] = f2bf(p2);
            Ps[prow][3 * 16 + mr] = f2bf(p3);
        }
        __asm__ __volatile__("s_waitcnt lgkmcnt(0)" ::: "memory");  // wave-local Ps RAW
#pragma unroll
        for (int st = 0; st < 2; st++) {
            const bf16x8 pf = *(const bf16x8*)&Ps[wave * 16 + mr][st * 32 + quad * 8];
#pragma unroll
            for (int j = 0; j < 4; j++) {
                const bf16x8 vf = *(const bf16x8*)&Vt[cur][j * 16 + mr][st * 32 + quad * 8];
                oacc[j] = MFMA_BF16(pf, vf, oacc[j]);
            }
        }
        if (kt < 15) {
            const int nxt = cur ^ 1;
            *(bf16x8*)&Ks[nxt][srow][sv * 8] = pk0;
            *(bf16x8*)&Ks[nxt][srow + 32][sv * 8] = pk1;
            *(bf16x8*)&Vt[nxt][srow][sv * 8] = pv0;
            *(bf16x8*)&Vt[nxt][srow + 32][sv * 8] = pv1;
        }
    }

#pragma unroll
    for (int r = 0; r < 4; r++) {
#pragma unroll
        for (int off = 1; off < 16; off <<= 1) lsum[r] += __shfl_xor(lsum[r], off);
        const float inv = 1.0f / lsum[r];
        u16* dst = ctx + (size_t)(b * 1024 + q0 + wave * 16 + quad * 4 + r) * 768 + h * 64;
#pragma unroll
        for (int j = 0; j < 4; j++) dst[j * 16 + mr] = f2bf(oacc[j][r] * inv);
    }
}

// ---------------------------------------------------------------------------
// Launcher. ws layout (bytes), base = d_ws + 1024:
//   xn/ctxb/hn @ +0         (25165824)
//   qkkb       @ +25165824  (50331648)  } h1 (100663296) overlays both
//   vtb        @ +75497472  (25165824)  } (dead after attention)
// core need = 125,830,144 (proven available in r5/r6).
// bf16 weights (14155776 B) appended iff ws_size >= 139,985,920; else the
// GEMMs fall back to in-staging fp32->bf16 B casts.
// ---------------------------------------------------------------------------
extern "C" void kernel_launch(void* const* d_in, const int* in_sizes, int n_in,
                              void* d_out, int out_size, void* d_ws, size_t ws_size,
                              hipStream_t stream) {
    const float* x      = (const float*)d_in[0];
    const float* ln1_g  = (const float*)d_in[1];
    const float* ln1_b  = (const float*)d_in[2];
    const float* qkv_w  = (const float*)d_in[3];
    const float* qkv_b  = (const float*)d_in[4];
    const float* proj_w = (const float*)d_in[5];
    const float* proj_b = (const float*)d_in[6];
    const float* ln2_g  = (const float*)d_in[7];
    const float* ln2_b  = (const float*)d_in[8];
    const float* fc1_w  = (const float*)d_in[9];
    const float* fc1_b  = (const float*)d_in[10];
    const float* fc2_w  = (const float*)d_in[11];
    const float* fc2_b  = (const float*)d_in[12];
    float* out = (float*)d_out;

    char* base = (char*)d_ws + 1024;
    u16* xn   = (u16*)base;                  // reused: ctxb, hn
    u16* qkkb = (u16*)(base + 25165824);
    u16* vtb  = (u16*)(base + 75497472);
    u16* h1   = (u16*)(base + 25165824);     // overlays qkkb+vtb
    u16* ctxb = xn;
    u16* hn   = xn;

    const size_t WOFF = 125830144ull;
    const bool big = ws_size >= 139985920ull;
    u16* wqkv  = (u16*)((char*)d_ws + WOFF);
    u16* wproj = (u16*)((char*)d_ws + WOFF + 3538944);
    u16* wfc1  = (u16*)((char*)d_ws + WOFF + 4718592);
    u16* wfc2  = (u16*)((char*)d_ws + WOFF + 9437184);

    if (big) {
        cast32<<<dim3(864),  dim3(256), 0, stream>>>(qkv_w,  wqkv,  221184);
        cast32<<<dim3(288),  dim3(256), 0, stream>>>(proj_w, wproj, 73728);
        cast32<<<dim3(1152), dim3(256), 0, stream>>>(fc1_w,  wfc1,  294912);
        cast32<<<dim3(1152), dim3(256), 0, stream>>>(fc2_w,  wfc2,  294912);
    }

    ln_kernel<<<dim3(16384), dim3(256), 0, stream>>>(x, ln1_g, ln1_b, xn);

    if (big)
        gemm3<3, 1><<<dim3(18, 128), dim3(256), 0, stream>>>(
            xn, wqkv, qkv_b, nullptr, qkkb, vtb, 2304, 768);
    else
        gemm3<3, 0><<<dim3(18, 128), dim3(256), 0, stream>>>(
            xn, qkv_w, qkv_b, nullptr, qkkb, vtb, 2304, 768);

    attn2<<<dim3(16, 192), dim3(256), 0, stream>>>(qkkb, vtb, ctxb);

    if (big)
        gemm3<2, 1><<<dim3(6, 128), dim3(256), 0, stream>>>(
            ctxb, wproj, proj_b, x, out, nullptr, 768, 768);
    else
        gemm3<2, 0><<<dim3(6, 128), dim3(256), 0, stream>>>(
            ctxb, proj_w, proj_b, x, out, nullptr, 768, 768);

    ln_kernel<<<dim3(16384), dim3(256), 0, stream>>>(out, ln2_g, ln2_b, hn);

    if (big)
        gemm3<1, 1><<<dim3(24, 128), dim3(256), 0, stream>>>(
            hn, wfc1, fc1_b, nullptr, h1, nullptr, 3072, 768);
    else
        gemm3<1, 0><<<dim3(24, 128), dim3(256), 0, stream>>>(
            hn, fc1_w, fc1_b, nullptr, h1, nullptr, 3072, 768);

    if (big)
        gemm3<2, 1><<<dim3(6, 128), dim3(256), 0, stream>>>(
            h1, wfc2, fc2_b, out, out, nullptr, 768, 3072);
    else
        gemm3<2, 0><<<dim3(6, 128), dim3(256), 0, stream>>>(
            h1, fc2_w, fc2_b, out, out, nullptr, 768, 3072);
}